// Round 2
// baseline (62.270 us; speedup 1.0000x reference)
//
#include <hip/hip_runtime.h>

// NormalComputer: out[b,:,i,j] = normalize(cross(up - down, right - left))
// Identity: sum of the 4 reference cross products == cross(up-down, right-left);
// center cancels; idx input never read (clamped indices recomputed from i,j).
// Vectorized: 4 pixels/thread, float4 loads/stores. A row is 1024 floats, so
// j0 = 4*k accesses are 16B-aligned. Edge clamp handled by 2 scalar loads.

#define HH 1024
#define WW 1024
#define BB 8
#define HW (HH * WW)

__global__ __launch_bounds__(256)
void normal_kernel(const float* __restrict__ in, float* __restrict__ out) {
    const int t = blockIdx.x * blockDim.x + threadIdx.x;   // 0 .. B*HW/4-1
    const int b  = t >> 18;                 // t / (HW/4)
    const int p4 = t & (HW / 4 - 1);
    const int i  = p4 >> 8;                 // row (256 groups of 4 per row)
    const int j0 = (p4 & 255) << 2;         // starting col of this 4-pixel group

    const int iu = (i > 0)      ? i - 1 : 0;
    const int id = (i < HH - 1) ? i + 1 : HH - 1;
    const int jL = (j0 > 0) ? j0 - 1 : 0;               // clamped left of j0
    const int jR = (j0 + 4 < WW) ? j0 + 4 : WW - 1;     // clamped right of j0+3

    const float* base = in + (size_t)b * 3 * HW;

    float ax[4][3], cx[4][3];
#pragma unroll
    for (int ch = 0; ch < 3; ++ch) {
        const float* pl = base + (size_t)ch * HW;
        const float4 up = *(const float4*)(pl + iu * WW + j0);
        const float4 dn = *(const float4*)(pl + id * WW + j0);
        const float4 md = *(const float4*)(pl + i  * WW + j0);
        const float lf  = pl[i * WW + jL];
        const float rt  = pl[i * WW + jR];

        ax[0][ch] = up.x - dn.x;
        ax[1][ch] = up.y - dn.y;
        ax[2][ch] = up.z - dn.z;
        ax[3][ch] = up.w - dn.w;

        cx[0][ch] = md.y - lf;
        cx[1][ch] = md.z - md.x;
        cx[2][ch] = md.w - md.y;
        cx[3][ch] = rt   - md.z;
    }

    float4 ox, oy, oz;
    float* rx = &ox.x; float* ry = &oy.x; float* rz = &oz.x;
#pragma unroll
    for (int k = 0; k < 4; ++k) {
        const float nx = ax[k][1] * cx[k][2] - ax[k][2] * cx[k][1];
        const float ny = ax[k][2] * cx[k][0] - ax[k][0] * cx[k][2];
        const float nz = ax[k][0] * cx[k][1] - ax[k][1] * cx[k][0];
        const float norm = sqrtf(nx * nx + ny * ny + nz * nz);
        const float inv  = 1.0f / fmaxf(norm, 1e-6f);
        rx[k] = nx * inv;
        ry[k] = ny * inv;
        rz[k] = nz * inv;
    }

    float* ob = out + (size_t)b * 3 * HW + i * WW + j0;
    *(float4*)(ob)          = ox;
    *(float4*)(ob + HW)     = oy;
    *(float4*)(ob + 2 * HW) = oz;
}

extern "C" void kernel_launch(void* const* d_in, const int* in_sizes, int n_in,
                              void* d_out, int out_size, void* d_ws, size_t ws_size,
                              hipStream_t stream) {
    const float* in = (const float*)d_in[0];
    float* out = (float*)d_out;
    const int total = BB * HW / 4;           // 2M threads, 4 px each
    const int block = 256;
    const int grid = total / block;          // 8192 blocks
    normal_kernel<<<grid, block, 0, stream>>>(in, out);
}

// Round 4
// 44.909 us; speedup vs baseline: 1.3866x; 1.3866x over previous
//
#include <hip/hip_runtime.h>

// NormalComputer: out[b,:,i,j] = normalize(cross(up - down, right - left))
// Identity: sum of 4 reference cross products == cross(up-down, right-left);
// center cancels; idx input never read (clamped indices recomputed from i,j).
//
// R3b: (a) XCD slab swizzle — each XCD gets one contiguous batch-image slab so
//      vertically-shared rows hit the same per-XCD L2 (fixes 1.56x over-fetch);
//      (b) 8 px/thread, float4 loads (MLP ~20 loads in flight);
//      (c) nontemporal stores (via clang ext_vector_type — HIP float4* is
//      rejected by the builtin) — output never re-read, keep L2 for inputs.

#define HH 1024
#define WW 1024
#define BB 8
#define HW (HH * WW)

typedef float floatx4 __attribute__((ext_vector_type(4)));

__global__ __launch_bounds__(256)
void normal_kernel(const float* __restrict__ in, float* __restrict__ out) {
    // 4096 blocks; bijective chunked XCD swizzle: XCD x gets blocks [x*512, (x+1)*512)
    const int nb = (blockIdx.x & 7) * 512 + (blockIdx.x >> 3);
    const int b  = nb >> 9;                    // 512 blocks per batch
    const int rp = nb & 511;                   // row-pair within batch
    const int tid = threadIdx.x;
    const int i  = rp * 2 + (tid >> 7);        // 2 rows per block
    const int j0 = (tid & 127) << 3;           // 8 px per thread

    const int iu = (i > 0)      ? i - 1 : 0;
    const int id = (i < HH - 1) ? i + 1 : HH - 1;
    const int jL = (j0 > 0) ? j0 - 1 : 0;
    const int jR = (j0 + 8 < WW) ? j0 + 8 : WW - 1;

    const float* base = in + (size_t)b * 3 * HW;

    float ax[8][3], cx[8][3];
#pragma unroll
    for (int ch = 0; ch < 3; ++ch) {
        const float* pl = base + (size_t)ch * HW;
        const floatx4 u0 = *(const floatx4*)(pl + iu * WW + j0);
        const floatx4 u1 = *(const floatx4*)(pl + iu * WW + j0 + 4);
        const floatx4 d0 = *(const floatx4*)(pl + id * WW + j0);
        const floatx4 d1 = *(const floatx4*)(pl + id * WW + j0 + 4);
        const floatx4 m0 = *(const floatx4*)(pl + i  * WW + j0);
        const floatx4 m1 = *(const floatx4*)(pl + i  * WW + j0 + 4);
        const float lf  = pl[i * WW + jL];
        const float rt  = pl[i * WW + jR];

        const float u[8] = {u0.x,u0.y,u0.z,u0.w,u1.x,u1.y,u1.z,u1.w};
        const float d[8] = {d0.x,d0.y,d0.z,d0.w,d1.x,d1.y,d1.z,d1.w};
        const float m[8] = {m0.x,m0.y,m0.z,m0.w,m1.x,m1.y,m1.z,m1.w};

#pragma unroll
        for (int k = 0; k < 8; ++k) ax[k][ch] = u[k] - d[k];
        cx[0][ch] = m[1] - lf;
#pragma unroll
        for (int k = 1; k < 7; ++k) cx[k][ch] = m[k + 1] - m[k - 1];
        cx[7][ch] = rt - m[6];
    }

    float rx[8], ry[8], rz[8];
#pragma unroll
    for (int k = 0; k < 8; ++k) {
        const float nx = ax[k][1] * cx[k][2] - ax[k][2] * cx[k][1];
        const float ny = ax[k][2] * cx[k][0] - ax[k][0] * cx[k][2];
        const float nz = ax[k][0] * cx[k][1] - ax[k][1] * cx[k][0];
        const float norm = sqrtf(nx * nx + ny * ny + nz * nz);
        const float inv  = 1.0f / fmaxf(norm, 1e-6f);
        rx[k] = nx * inv; ry[k] = ny * inv; rz[k] = nz * inv;
    }

    float* ob = out + (size_t)b * 3 * HW + i * WW + j0;
    floatx4* o0 = (floatx4*)(ob);
    floatx4* o1 = (floatx4*)(ob + HW);
    floatx4* o2 = (floatx4*)(ob + 2 * HW);
    floatx4 v;
    v = (floatx4){rx[0], rx[1], rx[2], rx[3]}; __builtin_nontemporal_store(v, o0);
    v = (floatx4){rx[4], rx[5], rx[6], rx[7]}; __builtin_nontemporal_store(v, o0 + 1);
    v = (floatx4){ry[0], ry[1], ry[2], ry[3]}; __builtin_nontemporal_store(v, o1);
    v = (floatx4){ry[4], ry[5], ry[6], ry[7]}; __builtin_nontemporal_store(v, o1 + 1);
    v = (floatx4){rz[0], rz[1], rz[2], rz[3]}; __builtin_nontemporal_store(v, o2);
    v = (floatx4){rz[4], rz[5], rz[6], rz[7]}; __builtin_nontemporal_store(v, o2 + 1);
}

extern "C" void kernel_launch(void* const* d_in, const int* in_sizes, int n_in,
                              void* d_out, int out_size, void* d_ws, size_t ws_size,
                              hipStream_t stream) {
    const float* in = (const float*)d_in[0];
    float* out = (float*)d_out;
    const int grid = BB * HW / (256 * 8);     // 4096 blocks, 8 px/thread
    normal_kernel<<<grid, 256, 0, stream>>>(in, out);
}

// Round 5
// 35.007 us; speedup vs baseline: 1.7788x; 1.2829x over previous
//
#include <hip/hip_runtime.h>

// NormalComputer: out[b,:,i,j] = normalize(cross(up - down, right - left))
// Identity: sum of 4 reference cross products == cross(up-down, right-left);
// center cancels; idx input never read (clamped indices recomputed from i,j).
//
// R5: (a) XCD slab swizzle kept — XCD x owns batch x (1024 contiguous rows),
//     so vertically-shared rows hit the same per-XCD L2 (FETCH 150->49 MB in R4);
//     (b) plain float4 stores — R4's nontemporal stores bypassed L2/L3 and paid
//     full HBM write cost; the Infinity Cache should absorb the 96 MB output
//     the same way it absorbs the input reads;
//     (c) 4 px/thread, 8192 blocks (one row per block) — 2x the TLP of R4.

#define HH 1024
#define WW 1024
#define BB 8
#define HW (HH * WW)

typedef float floatx4 __attribute__((ext_vector_type(4)));

__global__ __launch_bounds__(256)
void normal_kernel(const float* __restrict__ in, float* __restrict__ out) {
    // 8192 blocks; bijective chunked XCD swizzle: XCD x gets blocks [x*1024,(x+1)*1024)
    const int nb = (blockIdx.x & 7) * 1024 + (blockIdx.x >> 3);
    const int b = nb >> 10;                 // batch (== XCD index)
    const int i = nb & 1023;                // row
    const int j0 = threadIdx.x << 2;        // 4 px per thread, one row per block

    const int iu = (i > 0)      ? i - 1 : 0;
    const int id = (i < HH - 1) ? i + 1 : HH - 1;
    const int jL = (j0 > 0) ? j0 - 1 : 0;               // clamped left of j0
    const int jR = (j0 + 4 < WW) ? j0 + 4 : WW - 1;     // clamped right of j0+3

    const float* base = in + (size_t)b * 3 * HW;

    float ax[4][3], cx[4][3];
#pragma unroll
    for (int ch = 0; ch < 3; ++ch) {
        const float* pl = base + (size_t)ch * HW;
        const floatx4 up = *(const floatx4*)(pl + iu * WW + j0);
        const floatx4 dn = *(const floatx4*)(pl + id * WW + j0);
        const floatx4 md = *(const floatx4*)(pl + i  * WW + j0);
        const float lf  = pl[i * WW + jL];
        const float rt  = pl[i * WW + jR];

        ax[0][ch] = up.x - dn.x;
        ax[1][ch] = up.y - dn.y;
        ax[2][ch] = up.z - dn.z;
        ax[3][ch] = up.w - dn.w;

        cx[0][ch] = md.y - lf;
        cx[1][ch] = md.z - md.x;
        cx[2][ch] = md.w - md.y;
        cx[3][ch] = rt   - md.z;
    }

    floatx4 ox, oy, oz;
#pragma unroll
    for (int k = 0; k < 4; ++k) {
        const float nx = ax[k][1] * cx[k][2] - ax[k][2] * cx[k][1];
        const float ny = ax[k][2] * cx[k][0] - ax[k][0] * cx[k][2];
        const float nz = ax[k][0] * cx[k][1] - ax[k][1] * cx[k][0];
        const float norm = sqrtf(nx * nx + ny * ny + nz * nz);
        const float inv  = 1.0f / fmaxf(norm, 1e-6f);
        ox[k] = nx * inv; oy[k] = ny * inv; oz[k] = nz * inv;
    }

    float* ob = out + (size_t)b * 3 * HW + i * WW + j0;
    *(floatx4*)(ob)          = ox;
    *(floatx4*)(ob + HW)     = oy;
    *(floatx4*)(ob + 2 * HW) = oz;
}

extern "C" void kernel_launch(void* const* d_in, const int* in_sizes, int n_in,
                              void* d_out, int out_size, void* d_ws, size_t ws_size,
                              hipStream_t stream) {
    const float* in = (const float*)d_in[0];
    float* out = (float*)d_out;
    const int grid = BB * HH;                // 8192 blocks, one row each
    normal_kernel<<<grid, 256, 0, stream>>>(in, out);
}